// Round 2
// baseline (1960.634 us; speedup 1.0000x reference)
//
#include <hip/hip_runtime.h>
#include <math.h>

#define HH 256
#define WW 256
#define CC 64
#define PLANE (HH*WW)

// ---------------- conv 3x3 reflect, direct-global, software-pipelined ----------------
// thread = 8 horizontal pixels x 8 output channels; 2-deep ic pipeline (A/B windows)
// weights via wave-uniform addresses -> s_load (scalar pipe, free vs VALU)
__global__ __launch_bounds__(256, 3) void conv3x3_kernel(
    const float* __restrict__ in,    // [B,C,H,W]
    const float* __restrict__ w,     // [OC,IC,3,3]
    const float* __restrict__ bias,  // [OC]
    const float* __restrict__ prelu, // [OC] or null
    float* __restrict__ out,         // [B,OC,H,W]
    int do_prelu)
{
    const int tid = threadIdx.x;
    const int tx  = tid & 31;
    const int ty  = tid >> 5;
    const int x0  = tx << 3;                 // 0,8,...,248
    const int y   = (blockIdx.x << 3) + ty;  // 0..255
    const int ocg = blockIdx.y;              // 0..7 -> oc base ocg*8
    const int b   = blockIdx.z;

    // reflect-resolved neighbor rows / edge columns (computed ONCE)
    const int ym   = (y  == 0)   ? 1   : y - 1;
    const int yp   = (y  == 255) ? 254 : y + 1;
    const int colL = (x0 == 0)   ? 1   : x0 - 1;
    const int colR = (x0 == 248) ? 254 : x0 + 8;

    const int rA = ym * WW, rB = y * WW, rC = yp * WW;

    float acc[8][8];
#pragma unroll
    for (int i = 0; i < 8; i++)
#pragma unroll
        for (int j = 0; j < 8; j++) acc[i][j] = 0.f;

    const float* pin   = in + (size_t)b * CC * PLANE;
    const float* wbase = w + (size_t)(ocg * 8) * CC * 9;

    // two statically-named window buffers (no runtime indexing -> stays in VGPRs)
    float A0[10], A1[10], A2[10];
    float B0[10], B1[10], B2[10];

#define LOAD_ROW(W, roff, p_) { \
    const float4 q0 = *(const float4*)((p_) + (roff) + x0); \
    const float4 q1 = *(const float4*)((p_) + (roff) + x0 + 4); \
    W[0] = (p_)[(roff) + colL]; \
    W[1] = q0.x; W[2] = q0.y; W[3] = q0.z; W[4] = q0.w; \
    W[5] = q1.x; W[6] = q1.y; W[7] = q1.z; W[8] = q1.w; \
    W[9] = (p_)[(roff) + colR]; }

#define LOAD_WIN(W0, W1, W2, icv) { \
    const float* p_ = pin + (size_t)(icv) * PLANE; \
    LOAD_ROW(W0, rA, p_) \
    LOAD_ROW(W1, rB, p_) \
    LOAD_ROW(W2, rC, p_) }

#define FMA_ROW(W, w0, w1, w2, oc) { \
    _Pragma("unroll") \
    for (int q = 0; q < 8; q++) \
        acc[oc][q] = fmaf(w0, W[q], fmaf(w1, W[q+1], fmaf(w2, W[q+2], acc[oc][q]))); }

#define FMA_WIN(W0, W1, W2, icv) { \
    const float* wic = wbase + (size_t)(icv) * 9; \
    _Pragma("unroll") \
    for (int oc = 0; oc < 8; oc++) { \
        const float* wp = wic + (size_t)oc * CC * 9; \
        { const float w0 = wp[0], w1 = wp[1], w2 = wp[2]; FMA_ROW(W0, w0, w1, w2, oc) } \
        { const float w0 = wp[3], w1 = wp[4], w2 = wp[5]; FMA_ROW(W1, w0, w1, w2, oc) } \
        { const float w0 = wp[6], w1 = wp[7], w2 = wp[8]; FMA_ROW(W2, w0, w1, w2, oc) } } }

    LOAD_WIN(A0, A1, A2, 0)
#pragma unroll 1
    for (int ic = 0; ic < CC - 2; ic += 2) {
        LOAD_WIN(B0, B1, B2, ic + 1)   // prefetch ic+1 while computing ic
        FMA_WIN(A0, A1, A2, ic)
        LOAD_WIN(A0, A1, A2, ic + 2)   // prefetch ic+2 while computing ic+1
        FMA_WIN(B0, B1, B2, ic + 1)
    }
    LOAD_WIN(B0, B1, B2, CC - 1)
    FMA_WIN(A0, A1, A2, CC - 2)
    FMA_WIN(B0, B1, B2, CC - 1)

#undef LOAD_ROW
#undef LOAD_WIN
#undef FMA_ROW
#undef FMA_WIN

    const size_t obase = ((size_t)b * CC + ocg * 8) * PLANE + (size_t)y * WW + x0;
#pragma unroll
    for (int oc = 0; oc < 8; oc++) {
        const float bv = bias[ocg * 8 + oc];
        float v[8];
#pragma unroll
        for (int q = 0; q < 8; q++) v[q] = acc[oc][q] + bv;
        if (do_prelu) {
            const float a = prelu[ocg * 8 + oc];
#pragma unroll
            for (int q = 0; q < 8; q++)
                v[q] = fmaxf(v[q], 0.f) + a * fminf(v[q], 0.f);
        }
        float* o = out + obase + (size_t)oc * PLANE;
        *(float4*)(o)     = make_float4(v[0], v[1], v[2], v[3]);
        *(float4*)(o + 4) = make_float4(v[4], v[5], v[6], v[7]);
    }
}

// ---------------- fused: per-pixel channel mean/max + global avg pool ----------------
// one pass over r: amx[b,2,HW] and per-channel partial sums -> atomicAdd into g[b,c]
__global__ __launch_bounds__(256) void stats_kernel(
    const float* __restrict__ r, float* __restrict__ amx /*[B,2,HW]*/,
    float* __restrict__ g /*[B*C], pre-zeroed*/)
{
    const int tid = threadIdx.x;
    const int pix = blockIdx.x * 256 + tid;
    const int b = blockIdx.y;
    const int lane = tid & 63, wv = tid >> 6;
    __shared__ float gpart[4][64];

    const float* rb = r + (size_t)b * CC * PLANE + pix;
    float s = 0.f, m = -INFINITY;
    for (int c = 0; c < CC; c++) {
        float v = rb[(size_t)c * PLANE];
        s += v; m = fmaxf(m, v);
        float t = v;                       // wave-wide sum (64 pixels) for channel c
        t += __shfl_xor(t, 1, 64);
        t += __shfl_xor(t, 2, 64);
        t += __shfl_xor(t, 4, 64);
        t += __shfl_xor(t, 8, 64);
        t += __shfl_xor(t, 16, 64);
        t += __shfl_xor(t, 32, 64);
        if (lane == 0) gpart[wv][c] = t;
    }
    amx[(size_t)b * 2 * PLANE + pix] = s * (1.f / CC);
    amx[(size_t)b * 2 * PLANE + PLANE + pix] = m;
    __syncthreads();
    if (tid < 64) {
        float ps = (gpart[0][tid] + gpart[1][tid] + gpart[2][tid] + gpart[3][tid])
                   * (1.f / PLANE);
        atomicAdd(&g[b * 64 + tid], ps);
    }
}

// ---------------- spatial-attention 3x3 conv (2ch -> 1ch) ----------------
__global__ __launch_bounds__(256) void saconv_kernel(
    const float* __restrict__ amx, const float* __restrict__ sa_w,
    const float* __restrict__ sa_b, float* __restrict__ smap)
{
    int pix = blockIdx.x * 256 + threadIdx.x;
    int b = blockIdx.y;
    int x = pix & 255, y = pix >> 8;
    float acc = sa_b[0];
    const float* ab = amx + (size_t)b * 2 * PLANE;
#pragma unroll
    for (int c = 0; c < 2; c++)
#pragma unroll
        for (int dy = -1; dy <= 1; dy++)
#pragma unroll
            for (int dx = -1; dx <= 1; dx++) {
                int gx = x + dx; gx = gx < 0 ? 1 : (gx >= WW ? 2 * WW - 2 - gx : gx);
                int gy = y + dy; gy = gy < 0 ? 1 : (gy >= HH ? 2 * HH - 2 - gy : gy);
                acc += sa_w[c * 9 + (dy + 1) * 3 + (dx + 1)] * ab[(size_t)c * PLANE + gy * WW + gx];
            }
    smap[(size_t)b * PLANE + pix] = acc;
}

// ---------------- tiny MLPs: channel attention + hyper kernels ----------------
__global__ __launch_bounds__(256) void mlp_kernel(
    const float* __restrict__ h, const float* __restrict__ g,
    const float* __restrict__ ca_w1, const float* __restrict__ ca_b1,
    const float* __restrict__ ca_a,
    const float* __restrict__ ca_w2, const float* __restrict__ ca_b2,
    const float* __restrict__ fc_w, const float* __restrict__ fc_b,
    const float* __restrict__ k1_w, const float* __restrict__ k1_b,
    const float* __restrict__ k2_w, const float* __restrict__ k2_b,
    const float* __restrict__ k3_w, const float* __restrict__ k3_b,
    float* __restrict__ kernA, float* __restrict__ kernB /*[B,64,64]*/)
{
    int b = blockIdx.x, tid = threadIdx.x;
    __shared__ float gb[64], t16[16], u32[32], v32[32], cg1[32], casig[64];

    if (tid < 64) gb[tid] = g[b * 64 + tid];
    __syncthreads();

    if (tid < 16) {
        float s = fc_b[tid];
        for (int j = 0; j < 16; j++) s += fc_w[tid * 16 + j] * h[b * 16 + j];
        t16[tid] = s >= 0.f ? s : 0.01f * s;
    }
    if (tid < 32) {
        float c1 = ca_b1[tid];
        for (int j = 0; j < 64; j++) c1 += ca_w1[tid * 64 + j] * gb[j];
        cg1[tid] = fmaxf(c1, 0.f) + ca_a[tid] * fminf(c1, 0.f);
    }
    __syncthreads();
    if (tid < 32) {
        float s = k1_b[tid];
        for (int j = 0; j < 16; j++) s += k1_w[tid * 16 + j] * t16[j];
        u32[tid] = s >= 0.f ? s : 0.01f * s;
    }
    if (tid < 64) {
        float c2 = ca_b2[tid];
        for (int j = 0; j < 32; j++) c2 += ca_w2[tid * 32 + j] * cg1[j];
        casig[tid] = 1.f / (1.f + expf(-c2));
    }
    __syncthreads();
    if (tid < 32) {
        float s = k2_b[tid];
        for (int j = 0; j < 32; j++) s += k2_w[tid * 32 + j] * u32[j];
        v32[tid] = s >= 0.f ? s : 0.01f * s;
    }
    __syncthreads();
    // k3: 8192 outputs x 32 MACs; fold casig into the ca half
    for (int o = tid; o < 8192; o += 256) {
        float s = k3_b[o];
        for (int j = 0; j < 32; j++) s += k3_w[(size_t)o * 32 + j] * v32[j];
        int oc = o >> 7;       // /128
        int i = o & 127;
        if (i < 64) kernA[((size_t)b * 64 + oc) * 64 + i] = s;
        else        kernB[((size_t)b * 64 + oc) * 64 + (i - 64)] = s * casig[i - 64];
    }
}

// ---------------- final: out = x + hc_bias + sig(s)*(A.r) + (B.r) ----------------
__global__ __launch_bounds__(256) void final_kernel(
    const float* __restrict__ x, const float* __restrict__ r,
    const float* __restrict__ smap,
    const float* __restrict__ kernA, const float* __restrict__ kernB,
    const float* __restrict__ hc_bias,
    float* __restrict__ out)
{
    const int tid = threadIdx.x;
    const int pix = blockIdx.x * 256 + tid;
    const int og = blockIdx.y * 32;   // oc group: 0 or 32
    const int b = blockIdx.z;

    __shared__ float kA[64][32], kB[64][32]; // transposed [c][oc], 16 KiB
    for (int idx = tid; idx < 64 * 32; idx += 256) {
        int oc = idx & 31, c = idx >> 5;
        kA[c][oc] = kernA[((size_t)b * 64 + og + oc) * 64 + c];
        kB[c][oc] = kernB[((size_t)b * 64 + og + oc) * 64 + c];
    }
    __syncthreads();

    float accA[32], accB[32];
#pragma unroll
    for (int i = 0; i < 32; i++) { accA[i] = 0.f; accB[i] = 0.f; }

    const float* rb = r + (size_t)b * CC * PLANE + pix;
    for (int c = 0; c < CC; c++) {
        float rv = rb[(size_t)c * PLANE];
#pragma unroll
        for (int oc = 0; oc < 32; oc++) {
            accA[oc] += kA[c][oc] * rv;
            accB[oc] += kB[c][oc] * rv;
        }
    }

    float sv = smap[(size_t)b * PLANE + pix];
    float sig = 1.f / (1.f + expf(-sv));
    const float* xb = x + ((size_t)b * CC + og) * PLANE + pix;
    float* ob = out + ((size_t)b * CC + og) * PLANE + pix;
#pragma unroll
    for (int oc = 0; oc < 32; oc++) {
        ob[(size_t)oc * PLANE] = xb[(size_t)oc * PLANE] + hc_bias[og + oc]
                               + sig * accA[oc] + accB[oc];
    }
}

extern "C" void kernel_launch(void* const* d_in, const int* in_sizes, int n_in,
                              void* d_out, int out_size, void* d_ws, size_t ws_size,
                              hipStream_t stream) {
    const float* x   = (const float*)d_in[0];
    const float* h   = (const float*)d_in[1];
    const float* c1w = (const float*)d_in[2];
    const float* c1b = (const float*)d_in[3];
    const float* pa  = (const float*)d_in[4];
    const float* c2w = (const float*)d_in[5];
    const float* c2b = (const float*)d_in[6];
    const float* saw = (const float*)d_in[7];
    const float* sab = (const float*)d_in[8];
    const float* cw1 = (const float*)d_in[9];
    const float* cb1 = (const float*)d_in[10];
    const float* caa = (const float*)d_in[11];
    const float* cw2 = (const float*)d_in[12];
    const float* cb2 = (const float*)d_in[13];
    const float* fcw = (const float*)d_in[14];
    const float* fcb = (const float*)d_in[15];
    const float* k1w = (const float*)d_in[16];
    const float* k1b = (const float*)d_in[17];
    const float* k2w = (const float*)d_in[18];
    const float* k2b = (const float*)d_in[19];
    const float* k3w = (const float*)d_in[20];
    const float* k3b = (const float*)d_in[21];
    const float* hcb = (const float*)d_in[22];
    float* out = (float*)d_out;

    char* ws = (char*)d_ws;
    const size_t SZ_R = (size_t)8 * CC * PLANE * sizeof(float); // 134,217,728
    float* r1 = (float*)ws;
    float* r  = (float*)(ws + SZ_R);
    // r1 is dead after conv2 — reuse its space for the small buffers
    float* amx   = (float*)ws;                                    // 8*2*65536 f
    float* smap  = (float*)(ws + (size_t)8 * 2 * PLANE * 4);      // 8*65536 f
    float* g     = (float*)(ws + (size_t)8 * 3 * PLANE * 4);      // 512 f
    float* kernA = (float*)(ws + (size_t)8 * 3 * PLANE * 4 + 4096);
    float* kernB = kernA + (size_t)8 * 64 * 64;

    dim3 cgrid(HH / 8, CC / 8, 8); // (32 ytiles, 8 oc-groups, 8 batch)
    conv3x3_kernel<<<cgrid, 256, 0, stream>>>(x, c1w, c1b, pa, r1, 1);
    conv3x3_kernel<<<cgrid, 256, 0, stream>>>(r1, c2w, c2b, nullptr, r, 0);

    hipMemsetAsync(g, 0, 512 * sizeof(float), stream);
    stats_kernel<<<dim3(PLANE / 256, 8), 256, 0, stream>>>(r, amx, g);
    saconv_kernel<<<dim3(PLANE / 256, 8), 256, 0, stream>>>(amx, saw, sab, smap);
    mlp_kernel<<<8, 256, 0, stream>>>(h, g, cw1, cb1, caa, cw2, cb2,
                                      fcw, fcb, k1w, k1b, k2w, k2b, k3w, k3b,
                                      kernA, kernB);
    final_kernel<<<dim3(PLANE / 256, 2, 8), 256, 0, stream>>>(
        x, r, smap, kernA, kernB, hcb, out);
}

// Round 3
// 1438.147 us; speedup vs baseline: 1.3633x; 1.3633x over previous
//
#include <hip/hip_runtime.h>
#include <math.h>

#define HH 256
#define WW 256
#define CC 64
#define PLANE (HH*WW)

typedef float v2f __attribute__((ext_vector_type(2)));

// ---------------- conv 3x3 reflect: 4 px x 8 oc per thread ----------------
// variant A: packed float2 accumulators (targets v_pk_fma_f32 if HW supports)
__global__ __launch_bounds__(256) void conv3x3_pk(
    const float* __restrict__ in, const float* __restrict__ w,
    const float* __restrict__ bias, const float* __restrict__ prelu,
    float* __restrict__ out, int do_prelu)
{
    const int tid = threadIdx.x;
    const int tx  = tid & 31;
    const int ty  = tid >> 5;
    const int x0  = ((blockIdx.x & 1) << 7) + (tx << 2);   // 0..252 step 4
    const int y   = ((blockIdx.x >> 1) << 3) + ty;         // 0..255
    const int ocg = blockIdx.y;                            // 0..7
    const int b   = blockIdx.z;

    const int ym   = (y  == 0)   ? 1   : y - 1;
    const int yp   = (y  == 255) ? 254 : y + 1;
    const int colL = (x0 == 0)   ? 1   : x0 - 1;
    const int colR = (x0 == 252) ? 254 : x0 + 4;
    const int rA = ym * WW, rB = y * WW, rC = yp * WW;

    v2f acc[8][2];
#pragma unroll
    for (int i = 0; i < 8; i++) { acc[i][0] = (v2f){0.f, 0.f}; acc[i][1] = (v2f){0.f, 0.f}; }

    const float* pin   = in + (size_t)b * CC * PLANE;
    const float* wbase = w + (size_t)(ocg * 8) * CC * 9;

    for (int ic = 0; ic < CC; ic++) {
        const float* p = pin + (size_t)ic * PLANE;
        // window f0..f5 = [x0-1 .. x0+4]; shifted pairs for packed FMA
        v2f va[3], vb[3], vc[3], vd[3], ve[3];
#define LOADR(i, roff) { \
        const float4 q = *(const float4*)(p + (roff) + x0); \
        const float fl = p[(roff) + colL]; \
        const float fr = p[(roff) + colR]; \
        va[i] = (v2f){fl,  q.x}; vb[i] = (v2f){q.x, q.y}; \
        vc[i] = (v2f){q.y, q.z}; vd[i] = (v2f){q.z, q.w}; \
        ve[i] = (v2f){q.w, fr}; }
        LOADR(0, rA) LOADR(1, rB) LOADR(2, rC)
#undef LOADR

        const float* wic = wbase + (size_t)ic * 9;
#pragma unroll
        for (int oc = 0; oc < 8; oc++) {
            const float* wp = wic + (size_t)oc * CC * 9;  // uniform -> s_load
#pragma unroll
            for (int r = 0; r < 3; r++) {
                const float s0 = wp[r * 3 + 0], s1 = wp[r * 3 + 1], s2 = wp[r * 3 + 2];
                const v2f w0 = {s0, s0}, w1 = {s1, s1}, w2 = {s2, s2};
                acc[oc][0] = __builtin_elementwise_fma(w0, va[r],
                             __builtin_elementwise_fma(w1, vb[r],
                             __builtin_elementwise_fma(w2, vc[r], acc[oc][0])));
                acc[oc][1] = __builtin_elementwise_fma(w0, vc[r],
                             __builtin_elementwise_fma(w1, vd[r],
                             __builtin_elementwise_fma(w2, ve[r], acc[oc][1])));
            }
        }
    }

    const size_t obase = ((size_t)b * CC + ocg * 8) * PLANE + (size_t)y * WW + x0;
#pragma unroll
    for (int oc = 0; oc < 8; oc++) {
        const float bv = bias[ocg * 8 + oc];
        float v0 = acc[oc][0].x + bv, v1 = acc[oc][0].y + bv;
        float v2 = acc[oc][1].x + bv, v3 = acc[oc][1].y + bv;
        if (do_prelu) {
            const float a = prelu[ocg * 8 + oc];
            v0 = fmaxf(v0, 0.f) + a * fminf(v0, 0.f);
            v1 = fmaxf(v1, 0.f) + a * fminf(v1, 0.f);
            v2 = fmaxf(v2, 0.f) + a * fminf(v2, 0.f);
            v3 = fmaxf(v3, 0.f) + a * fminf(v3, 0.f);
        }
        *(float4*)(out + obase + (size_t)oc * PLANE) = make_float4(v0, v1, v2, v3);
    }
}

// variant B: scalar FMA reference structure (same geometry)
__global__ __launch_bounds__(256) void conv3x3_sc(
    const float* __restrict__ in, const float* __restrict__ w,
    const float* __restrict__ bias, const float* __restrict__ prelu,
    float* __restrict__ out, int do_prelu)
{
    const int tid = threadIdx.x;
    const int tx  = tid & 31;
    const int ty  = tid >> 5;
    const int x0  = ((blockIdx.x & 1) << 7) + (tx << 2);
    const int y   = ((blockIdx.x >> 1) << 3) + ty;
    const int ocg = blockIdx.y;
    const int b   = blockIdx.z;

    const int ym   = (y  == 0)   ? 1   : y - 1;
    const int yp   = (y  == 255) ? 254 : y + 1;
    const int colL = (x0 == 0)   ? 1   : x0 - 1;
    const int colR = (x0 == 252) ? 254 : x0 + 4;
    const int rA = ym * WW, rB = y * WW, rC = yp * WW;

    float acc[8][4];
#pragma unroll
    for (int i = 0; i < 8; i++)
#pragma unroll
        for (int j = 0; j < 4; j++) acc[i][j] = 0.f;

    const float* pin   = in + (size_t)b * CC * PLANE;
    const float* wbase = w + (size_t)(ocg * 8) * CC * 9;

    for (int ic = 0; ic < CC; ic++) {
        const float* p = pin + (size_t)ic * PLANE;
        float win[3][6];
#define LOADR(i, roff) { \
        const float4 q = *(const float4*)(p + (roff) + x0); \
        win[i][0] = p[(roff) + colL]; \
        win[i][1] = q.x; win[i][2] = q.y; win[i][3] = q.z; win[i][4] = q.w; \
        win[i][5] = p[(roff) + colR]; }
        LOADR(0, rA) LOADR(1, rB) LOADR(2, rC)
#undef LOADR

        const float* wic = wbase + (size_t)ic * 9;
#pragma unroll
        for (int oc = 0; oc < 8; oc++) {
            const float* wp = wic + (size_t)oc * CC * 9;
#pragma unroll
            for (int r = 0; r < 3; r++) {
                const float w0 = wp[r * 3 + 0], w1 = wp[r * 3 + 1], w2 = wp[r * 3 + 2];
#pragma unroll
                for (int q = 0; q < 4; q++)
                    acc[oc][q] = fmaf(w0, win[r][q],
                                 fmaf(w1, win[r][q + 1],
                                 fmaf(w2, win[r][q + 2], acc[oc][q])));
            }
        }
    }

    const size_t obase = ((size_t)b * CC + ocg * 8) * PLANE + (size_t)y * WW + x0;
#pragma unroll
    for (int oc = 0; oc < 8; oc++) {
        const float bv = bias[ocg * 8 + oc];
        float v[4];
#pragma unroll
        for (int q = 0; q < 4; q++) v[q] = acc[oc][q] + bv;
        if (do_prelu) {
            const float a = prelu[ocg * 8 + oc];
#pragma unroll
            for (int q = 0; q < 4; q++)
                v[q] = fmaxf(v[q], 0.f) + a * fminf(v[q], 0.f);
        }
        *(float4*)(out + obase + (size_t)oc * PLANE) = make_float4(v[0], v[1], v[2], v[3]);
    }
}

// ---------------- fused: per-pixel channel mean/max + global avg pool ----------------
__global__ __launch_bounds__(256) void stats_kernel(
    const float* __restrict__ r, float* __restrict__ amx /*[B,2,HW]*/,
    float* __restrict__ g /*[B*C], pre-zeroed*/)
{
    const int tid = threadIdx.x;
    const int pix = blockIdx.x * 256 + tid;
    const int b = blockIdx.y;
    const int lane = tid & 63, wv = tid >> 6;
    __shared__ float gpart[4][64];

    const float* rb = r + (size_t)b * CC * PLANE + pix;
    float s = 0.f, m = -INFINITY;
    for (int c = 0; c < CC; c++) {
        float v = rb[(size_t)c * PLANE];
        s += v; m = fmaxf(m, v);
        float t = v;
        t += __shfl_xor(t, 1, 64);
        t += __shfl_xor(t, 2, 64);
        t += __shfl_xor(t, 4, 64);
        t += __shfl_xor(t, 8, 64);
        t += __shfl_xor(t, 16, 64);
        t += __shfl_xor(t, 32, 64);
        if (lane == 0) gpart[wv][c] = t;
    }
    amx[(size_t)b * 2 * PLANE + pix] = s * (1.f / CC);
    amx[(size_t)b * 2 * PLANE + PLANE + pix] = m;
    __syncthreads();
    if (tid < 64) {
        float ps = (gpart[0][tid] + gpart[1][tid] + gpart[2][tid] + gpart[3][tid])
                   * (1.f / PLANE);
        atomicAdd(&g[b * 64 + tid], ps);
    }
}

// ---------------- spatial-attention 3x3 conv (2ch -> 1ch) ----------------
__global__ __launch_bounds__(256) void saconv_kernel(
    const float* __restrict__ amx, const float* __restrict__ sa_w,
    const float* __restrict__ sa_b, float* __restrict__ smap)
{
    int pix = blockIdx.x * 256 + threadIdx.x;
    int b = blockIdx.y;
    int x = pix & 255, y = pix >> 8;
    float acc = sa_b[0];
    const float* ab = amx + (size_t)b * 2 * PLANE;
#pragma unroll
    for (int c = 0; c < 2; c++)
#pragma unroll
        for (int dy = -1; dy <= 1; dy++)
#pragma unroll
            for (int dx = -1; dx <= 1; dx++) {
                int gx = x + dx; gx = gx < 0 ? 1 : (gx >= WW ? 2 * WW - 2 - gx : gx);
                int gy = y + dy; gy = gy < 0 ? 1 : (gy >= HH ? 2 * HH - 2 - gy : gy);
                acc += sa_w[c * 9 + (dy + 1) * 3 + (dx + 1)] * ab[(size_t)c * PLANE + gy * WW + gx];
            }
    smap[(size_t)b * PLANE + pix] = acc;
}

// ---------------- tiny MLPs: channel attention + hyper kernels ----------------
__global__ __launch_bounds__(256) void mlp_kernel(
    const float* __restrict__ h, const float* __restrict__ g,
    const float* __restrict__ ca_w1, const float* __restrict__ ca_b1,
    const float* __restrict__ ca_a,
    const float* __restrict__ ca_w2, const float* __restrict__ ca_b2,
    const float* __restrict__ fc_w, const float* __restrict__ fc_b,
    const float* __restrict__ k1_w, const float* __restrict__ k1_b,
    const float* __restrict__ k2_w, const float* __restrict__ k2_b,
    const float* __restrict__ k3_w, const float* __restrict__ k3_b,
    float* __restrict__ kernA, float* __restrict__ kernB /*[B,64,64]*/)
{
    int b = blockIdx.x, tid = threadIdx.x;
    __shared__ float gb[64], t16[16], u32[32], v32[32], cg1[32], casig[64];

    if (tid < 64) gb[tid] = g[b * 64 + tid];
    __syncthreads();

    if (tid < 16) {
        float s = fc_b[tid];
        for (int j = 0; j < 16; j++) s += fc_w[tid * 16 + j] * h[b * 16 + j];
        t16[tid] = s >= 0.f ? s : 0.01f * s;
    }
    if (tid < 32) {
        float c1 = ca_b1[tid];
        for (int j = 0; j < 64; j++) c1 += ca_w1[tid * 64 + j] * gb[j];
        cg1[tid] = fmaxf(c1, 0.f) + ca_a[tid] * fminf(c1, 0.f);
    }
    __syncthreads();
    if (tid < 32) {
        float s = k1_b[tid];
        for (int j = 0; j < 16; j++) s += k1_w[tid * 16 + j] * t16[j];
        u32[tid] = s >= 0.f ? s : 0.01f * s;
    }
    if (tid < 64) {
        float c2 = ca_b2[tid];
        for (int j = 0; j < 32; j++) c2 += ca_w2[tid * 32 + j] * cg1[j];
        casig[tid] = 1.f / (1.f + expf(-c2));
    }
    __syncthreads();
    if (tid < 32) {
        float s = k2_b[tid];
        for (int j = 0; j < 32; j++) s += k2_w[tid * 32 + j] * u32[j];
        v32[tid] = s >= 0.f ? s : 0.01f * s;
    }
    __syncthreads();
    for (int o = tid; o < 8192; o += 256) {
        float s = k3_b[o];
        for (int j = 0; j < 32; j++) s += k3_w[(size_t)o * 32 + j] * v32[j];
        int oc = o >> 7;
        int i = o & 127;
        if (i < 64) kernA[((size_t)b * 64 + oc) * 64 + i] = s;
        else        kernB[((size_t)b * 64 + oc) * 64 + (i - 64)] = s * casig[i - 64];
    }
}

// ---------------- final: out = x + hc_bias + sig(s)*(A.r) + (B.r) ----------------
__global__ __launch_bounds__(256) void final_kernel(
    const float* __restrict__ x, const float* __restrict__ r,
    const float* __restrict__ smap,
    const float* __restrict__ kernA, const float* __restrict__ kernB,
    const float* __restrict__ hc_bias,
    float* __restrict__ out)
{
    const int tid = threadIdx.x;
    const int pix = blockIdx.x * 256 + tid;
    const int og = blockIdx.y * 32;
    const int b = blockIdx.z;

    __shared__ float kA[64][32], kB[64][32];
    for (int idx = tid; idx < 64 * 32; idx += 256) {
        int oc = idx & 31, c = idx >> 5;
        kA[c][oc] = kernA[((size_t)b * 64 + og + oc) * 64 + c];
        kB[c][oc] = kernB[((size_t)b * 64 + og + oc) * 64 + c];
    }
    __syncthreads();

    float accA[32], accB[32];
#pragma unroll
    for (int i = 0; i < 32; i++) { accA[i] = 0.f; accB[i] = 0.f; }

    const float* rb = r + (size_t)b * CC * PLANE + pix;
    for (int c = 0; c < CC; c++) {
        float rv = rb[(size_t)c * PLANE];
#pragma unroll
        for (int oc = 0; oc < 32; oc++) {
            accA[oc] += kA[c][oc] * rv;
            accB[oc] += kB[c][oc] * rv;
        }
    }

    float sv = smap[(size_t)b * PLANE + pix];
    float sig = 1.f / (1.f + expf(-sv));
    const float* xb = x + ((size_t)b * CC + og) * PLANE + pix;
    float* ob = out + ((size_t)b * CC + og) * PLANE + pix;
#pragma unroll
    for (int oc = 0; oc < 32; oc++) {
        ob[(size_t)oc * PLANE] = xb[(size_t)oc * PLANE] + hc_bias[og + oc]
                               + sig * accA[oc] + accB[oc];
    }
}

extern "C" void kernel_launch(void* const* d_in, const int* in_sizes, int n_in,
                              void* d_out, int out_size, void* d_ws, size_t ws_size,
                              hipStream_t stream) {
    const float* x   = (const float*)d_in[0];
    const float* h   = (const float*)d_in[1];
    const float* c1w = (const float*)d_in[2];
    const float* c1b = (const float*)d_in[3];
    const float* pa  = (const float*)d_in[4];
    const float* c2w = (const float*)d_in[5];
    const float* c2b = (const float*)d_in[6];
    const float* saw = (const float*)d_in[7];
    const float* sab = (const float*)d_in[8];
    const float* cw1 = (const float*)d_in[9];
    const float* cb1 = (const float*)d_in[10];
    const float* caa = (const float*)d_in[11];
    const float* cw2 = (const float*)d_in[12];
    const float* cb2 = (const float*)d_in[13];
    const float* fcw = (const float*)d_in[14];
    const float* fcb = (const float*)d_in[15];
    const float* k1w = (const float*)d_in[16];
    const float* k1b = (const float*)d_in[17];
    const float* k2w = (const float*)d_in[18];
    const float* k2b = (const float*)d_in[19];
    const float* k3w = (const float*)d_in[20];
    const float* k3b = (const float*)d_in[21];
    const float* hcb = (const float*)d_in[22];
    float* out = (float*)d_out;

    char* ws = (char*)d_ws;
    const size_t SZ_R = (size_t)8 * CC * PLANE * sizeof(float); // 134,217,728
    float* r1 = (float*)ws;
    float* r  = (float*)(ws + SZ_R);
    float* amx   = (float*)ws;
    float* smap  = (float*)(ws + (size_t)8 * 2 * PLANE * 4);
    float* g     = (float*)(ws + (size_t)8 * 3 * PLANE * 4);
    float* kernA = (float*)(ws + (size_t)8 * 3 * PLANE * 4 + 4096);
    float* kernB = kernA + (size_t)8 * 64 * 64;

    dim3 cgrid(64, 8, 8); // (2 xtiles * 32 ytiles, 8 oc-groups, 8 batch)
    conv3x3_pk<<<cgrid, 256, 0, stream>>>(x, c1w, c1b, pa, r1, 1);   // A/B: packed
    conv3x3_sc<<<cgrid, 256, 0, stream>>>(r1, c2w, c2b, nullptr, r, 0); // A/B: scalar

    hipMemsetAsync(g, 0, 512 * sizeof(float), stream);
    stats_kernel<<<dim3(PLANE / 256, 8), 256, 0, stream>>>(r, amx, g);
    saconv_kernel<<<dim3(PLANE / 256, 8), 256, 0, stream>>>(amx, saw, sab, smap);
    mlp_kernel<<<8, 256, 0, stream>>>(h, g, cw1, cb1, caa, cw2, cb2,
                                      fcw, fcb, k1w, k1b, k2w, k2b, k3w, k3b,
                                      kernA, kernB);
    final_kernel<<<dim3(PLANE / 256, 2, 8), 256, 0, stream>>>(
        x, r, smap, kernA, kernB, hcb, out);
}

// Round 4
// 1056.243 us; speedup vs baseline: 1.8562x; 1.3616x over previous
//
#include <hip/hip_runtime.h>
#include <math.h>

#define HH 256
#define WW 256
#define CC 64
#define PLANE (HH*WW)

typedef short s16x8 __attribute__((ext_vector_type(8)));
typedef float f32x16 __attribute__((ext_vector_type(16)));
typedef unsigned int uint;
typedef uint u32x4v __attribute__((ext_vector_type(4)));

__device__ inline uint bf16rne(float f) {
    uint u = __float_as_uint(f);
    return (u + 0x7FFFu + ((u >> 16) & 1u)) >> 16;
}
__device__ inline float bf16val(uint h) { return __uint_as_float(h << 16); }
__device__ inline s16x8 fragpack(uint a, uint b, uint c, uint d) {
    u32x4v t = {a, b, c, d};
    return __builtin_bit_cast(s16x8, t);
}

// ---------------- weight prep: split fp32 W into bf16 hi/lo, pack ic-pairs ----
// layout: wh/wl [tap][oc][icpair] dwords; dword = bf16(ic even) | bf16(ic odd)<<16
__global__ __launch_bounds__(256) void wprep_kernel(
    const float* __restrict__ w1, const float* __restrict__ w2,
    uint* __restrict__ wh1, uint* __restrict__ wl1,
    uint* __restrict__ wh2, uint* __restrict__ wl2)
{
    const int idx = blockIdx.x * 256 + threadIdx.x;      // 0..18431
    const float* w = blockIdx.y ? w2 : w1;
    uint* wh = blockIdx.y ? wh2 : wh1;
    uint* wl = blockIdx.y ? wl2 : wl1;
    const int tap = idx >> 11;           // 9
    const int oc  = (idx >> 5) & 63;     // 64
    const int icp = idx & 31;            // 32 ic-pairs
    float w0 = w[(oc * 64 + 2 * icp) * 9 + tap];
    float w1v = w[(oc * 64 + 2 * icp + 1) * 9 + tap];
    uint h0 = bf16rne(w0); float l0 = w0 - bf16val(h0);
    uint h1 = bf16rne(w1v); float l1 = w1v - bf16val(h1);
    wh[idx] = h0 | (h1 << 16);
    wl[idx] = bf16rne(l0) | (bf16rne(l1) << 16);
}

// ---------------- conv 3x3 reflect via MFMA implicit GEMM ----------------
// block: 256 thr = 4 waves; tile 64 oc x 8 rows x 32 cols
// LDS: X tile bf16 ic-pair packed, [340 px][34 dw] (pad -> 2-way banks, free)
// wave w: rows {2w, 2w+1}; per (tap, kchunk): 2 ds_read_b64 x2rows (B),
// 4 global dwordx4 (A hi/lo x 2 Mtiles), 8 mfma_32x32x16_bf16
// MODE 1: fp32 in (x), PReLU, bf16-packed out. MODE 2: packed in, fp32 out.
template<int MODE>
__global__ __launch_bounds__(256, 3) void conv_mfma(
    const float* __restrict__ xf, const uint* __restrict__ xp,
    const uint* __restrict__ wh, const uint* __restrict__ wl,
    const float* __restrict__ bias, const float* __restrict__ prelu,
    uint* __restrict__ op, float* __restrict__ of)
{
    __shared__ uint lds[340 * 34];
    const int tid  = threadIdx.x;
    const int lane = tid & 63;
    const int wid  = tid >> 6;
    const int x0 = blockIdx.x * 32;
    const int yt = blockIdx.y * 8;
    const int b  = blockIdx.z;

    // ---- stage halo tile (reflect pad 1): rows 0..9, cols 0..33, icpair 0..31
    {
        const int col = lane;            // lanes 0..33 active
        int gx = x0 - 1 + col;
        gx = gx < 0 ? 1 : (gx > 255 ? 254 : gx);
        for (int t = wid; t < 320; t += 4) {
            const int row = t >> 5;      // 0..9
            const int icp = t & 31;
            int gy = yt - 1 + row;
            gy = gy < 0 ? 1 : (gy > 255 ? 254 : gy);
            if (col < 34) {
                uint pk;
                if (MODE == 1) {
                    float v0 = xf[(((size_t)b * 64 + 2 * icp) * 256 + gy) * 256 + gx];
                    float v1 = xf[(((size_t)b * 64 + 2 * icp + 1) * 256 + gy) * 256 + gx];
                    pk = bf16rne(v0) | (bf16rne(v1) << 16);
                } else {
                    pk = xp[(((size_t)b * 32 + icp) * 256 + gy) * 256 + gx];
                }
                lds[(row * 34 + col) * 34 + icp] = pk;
            }
        }
    }
    __syncthreads();

    // ---- MFMA main loop
    f32x16 acc00 = (f32x16)0.f, acc01 = (f32x16)0.f;   // [Mtile][row]
    f32x16 acc10 = (f32x16)0.f, acc11 = (f32x16)0.f;
    const int colx = lane & 31;
    const int half = lane >> 5;
    const int r0 = wid * 2;

#pragma unroll
    for (int tap = 0; tap < 9; tap++) {
        const int dy = tap / 3, dx = tap % 3;
        const uint* lp0 = &lds[((r0 + dy) * 34 + dx + colx) * 34];
        const uint* lp1 = lp0 + 34 * 34;                        // next out-row
        const uint* wbh = wh + ((size_t)tap * 64 + colx) * 32 + half * 4;
        const uint* wbl = wl + ((size_t)tap * 64 + colx) * 32 + half * 4;
#pragma unroll
        for (int c = 0; c < 4; c++) {
            const int bo = c * 8 + half * 4;
            const uint2 q0 = *(const uint2*)(lp0 + bo);
            const uint2 q1 = *(const uint2*)(lp0 + bo + 2);
            const uint2 q2 = *(const uint2*)(lp1 + bo);
            const uint2 q3 = *(const uint2*)(lp1 + bo + 2);
            const s16x8 B0 = fragpack(q0.x, q0.y, q1.x, q1.y);
            const s16x8 B1 = fragpack(q2.x, q2.y, q3.x, q3.y);
            const uint4 ah0 = *(const uint4*)(wbh + c * 8);
            const uint4 al0 = *(const uint4*)(wbl + c * 8);
            const uint4 ah1 = *(const uint4*)(wbh + 1024 + c * 8);
            const uint4 al1 = *(const uint4*)(wbl + 1024 + c * 8);
            const s16x8 A0h = fragpack(ah0.x, ah0.y, ah0.z, ah0.w);
            const s16x8 A0l = fragpack(al0.x, al0.y, al0.z, al0.w);
            const s16x8 A1h = fragpack(ah1.x, ah1.y, ah1.z, ah1.w);
            const s16x8 A1l = fragpack(al1.x, al1.y, al1.z, al1.w);
            acc00 = __builtin_amdgcn_mfma_f32_32x32x16_bf16(A0h, B0, acc00, 0, 0, 0);
            acc01 = __builtin_amdgcn_mfma_f32_32x32x16_bf16(A0h, B1, acc01, 0, 0, 0);
            acc10 = __builtin_amdgcn_mfma_f32_32x32x16_bf16(A1h, B0, acc10, 0, 0, 0);
            acc11 = __builtin_amdgcn_mfma_f32_32x32x16_bf16(A1h, B1, acc11, 0, 0, 0);
            acc00 = __builtin_amdgcn_mfma_f32_32x32x16_bf16(A0l, B0, acc00, 0, 0, 0);
            acc01 = __builtin_amdgcn_mfma_f32_32x32x16_bf16(A0l, B1, acc01, 0, 0, 0);
            acc10 = __builtin_amdgcn_mfma_f32_32x32x16_bf16(A1l, B0, acc10, 0, 0, 0);
            acc11 = __builtin_amdgcn_mfma_f32_32x32x16_bf16(A1l, B1, acc11, 0, 0, 0);
        }
    }

    // ---- epilogue: C/D layout (32x32): col=lane&31, row=(j&3)+8*(j>>2)+4*half
    const int y0 = yt + r0;
    const int xg = x0 + colx;

#define EPI1(ACC, MT, RR) { \
    const int yy = y0 + RR; \
    _Pragma("unroll") \
    for (int j = 0; j < 16; j += 2) { \
        const int row = (j & 3) + 8 * (j >> 2) + 4 * half; \
        const int oc = MT * 32 + row; \
        float v0 = ACC[j]     + bias[oc]; \
        float v1 = ACC[j + 1] + bias[oc + 1]; \
        const float a0 = prelu[oc], a1 = prelu[oc + 1]; \
        v0 = fmaxf(v0, 0.f) + a0 * fminf(v0, 0.f); \
        v1 = fmaxf(v1, 0.f) + a1 * fminf(v1, 0.f); \
        op[(((size_t)b * 32 + (oc >> 1)) * 256 + yy) * 256 + xg] = \
            bf16rne(v0) | (bf16rne(v1) << 16); \
    } }
#define EPI2(ACC, MT, RR) { \
    const int yy = y0 + RR; \
    _Pragma("unroll") \
    for (int j = 0; j < 16; j++) { \
        const int row = (j & 3) + 8 * (j >> 2) + 4 * half; \
        const int oc = MT * 32 + row; \
        of[(((size_t)b * 64 + oc) * 256 + yy) * 256 + xg] = ACC[j] + bias[oc]; \
    } }

    if constexpr (MODE == 1) {
        EPI1(acc00, 0, 0) EPI1(acc01, 0, 1) EPI1(acc10, 1, 0) EPI1(acc11, 1, 1)
    } else {
        EPI2(acc00, 0, 0) EPI2(acc01, 0, 1) EPI2(acc10, 1, 0) EPI2(acc11, 1, 1)
    }
#undef EPI1
#undef EPI2
}

// ---------------- fused: per-pixel channel mean/max + global avg pool ----------------
__global__ __launch_bounds__(256) void stats_kernel(
    const float* __restrict__ r, float* __restrict__ amx /*[B,2,HW]*/,
    float* __restrict__ g /*[B*C], pre-zeroed*/)
{
    const int tid = threadIdx.x;
    const int pix = blockIdx.x * 256 + tid;
    const int b = blockIdx.y;
    const int lane = tid & 63, wv = tid >> 6;
    __shared__ float gpart[4][64];

    const float* rb = r + (size_t)b * CC * PLANE + pix;
    float s = 0.f, m = -INFINITY;
    for (int c = 0; c < CC; c++) {
        float v = rb[(size_t)c * PLANE];
        s += v; m = fmaxf(m, v);
        float t = v;
        t += __shfl_xor(t, 1, 64);
        t += __shfl_xor(t, 2, 64);
        t += __shfl_xor(t, 4, 64);
        t += __shfl_xor(t, 8, 64);
        t += __shfl_xor(t, 16, 64);
        t += __shfl_xor(t, 32, 64);
        if (lane == 0) gpart[wv][c] = t;
    }
    amx[(size_t)b * 2 * PLANE + pix] = s * (1.f / CC);
    amx[(size_t)b * 2 * PLANE + PLANE + pix] = m;
    __syncthreads();
    if (tid < 64) {
        float ps = (gpart[0][tid] + gpart[1][tid] + gpart[2][tid] + gpart[3][tid])
                   * (1.f / PLANE);
        atomicAdd(&g[b * 64 + tid], ps);
    }
}

// ---------------- spatial-attention 3x3 conv (2ch -> 1ch) ----------------
__global__ __launch_bounds__(256) void saconv_kernel(
    const float* __restrict__ amx, const float* __restrict__ sa_w,
    const float* __restrict__ sa_b, float* __restrict__ smap)
{
    int pix = blockIdx.x * 256 + threadIdx.x;
    int b = blockIdx.y;
    int x = pix & 255, y = pix >> 8;
    float acc = sa_b[0];
    const float* ab = amx + (size_t)b * 2 * PLANE;
#pragma unroll
    for (int c = 0; c < 2; c++)
#pragma unroll
        for (int dy = -1; dy <= 1; dy++)
#pragma unroll
            for (int dx = -1; dx <= 1; dx++) {
                int gx = x + dx; gx = gx < 0 ? 1 : (gx >= WW ? 2 * WW - 2 - gx : gx);
                int gy = y + dy; gy = gy < 0 ? 1 : (gy >= HH ? 2 * HH - 2 - gy : gy);
                acc += sa_w[c * 9 + (dy + 1) * 3 + (dx + 1)] * ab[(size_t)c * PLANE + gy * WW + gx];
            }
    smap[(size_t)b * PLANE + pix] = acc;
}

// ---------------- tiny MLPs: channel attention + hyper kernels ----------------
__global__ __launch_bounds__(256) void mlp_kernel(
    const float* __restrict__ h, const float* __restrict__ g,
    const float* __restrict__ ca_w1, const float* __restrict__ ca_b1,
    const float* __restrict__ ca_a,
    const float* __restrict__ ca_w2, const float* __restrict__ ca_b2,
    const float* __restrict__ fc_w, const float* __restrict__ fc_b,
    const float* __restrict__ k1_w, const float* __restrict__ k1_b,
    const float* __restrict__ k2_w, const float* __restrict__ k2_b,
    const float* __restrict__ k3_w, const float* __restrict__ k3_b,
    float* __restrict__ kernA, float* __restrict__ kernB /*[B,64,64]*/)
{
    int b = blockIdx.x, tid = threadIdx.x;
    __shared__ float gb[64], t16[16], u32[32], v32[32], cg1[32], casig[64];

    if (tid < 64) gb[tid] = g[b * 64 + tid];
    __syncthreads();

    if (tid < 16) {
        float s = fc_b[tid];
        for (int j = 0; j < 16; j++) s += fc_w[tid * 16 + j] * h[b * 16 + j];
        t16[tid] = s >= 0.f ? s : 0.01f * s;
    }
    if (tid < 32) {
        float c1 = ca_b1[tid];
        for (int j = 0; j < 64; j++) c1 += ca_w1[tid * 64 + j] * gb[j];
        cg1[tid] = fmaxf(c1, 0.f) + ca_a[tid] * fminf(c1, 0.f);
    }
    __syncthreads();
    if (tid < 32) {
        float s = k1_b[tid];
        for (int j = 0; j < 16; j++) s += k1_w[tid * 16 + j] * t16[j];
        u32[tid] = s >= 0.f ? s : 0.01f * s;
    }
    if (tid < 64) {
        float c2 = ca_b2[tid];
        for (int j = 0; j < 32; j++) c2 += ca_w2[tid * 32 + j] * cg1[j];
        casig[tid] = 1.f / (1.f + expf(-c2));
    }
    __syncthreads();
    if (tid < 32) {
        float s = k2_b[tid];
        for (int j = 0; j < 32; j++) s += k2_w[tid * 32 + j] * u32[j];
        v32[tid] = s >= 0.f ? s : 0.01f * s;
    }
    __syncthreads();
    for (int o = tid; o < 8192; o += 256) {
        float s = k3_b[o];
        for (int j = 0; j < 32; j++) s += k3_w[(size_t)o * 32 + j] * v32[j];
        int oc = o >> 7;
        int i = o & 127;
        if (i < 64) kernA[((size_t)b * 64 + oc) * 64 + i] = s;
        else        kernB[((size_t)b * 64 + oc) * 64 + (i - 64)] = s * casig[i - 64];
    }
}

// ---------------- final: out = x + hc_bias + sig(s)*(A.r) + (B.r) ----------------
__global__ __launch_bounds__(256) void final_kernel(
    const float* __restrict__ x, const float* __restrict__ r,
    const float* __restrict__ smap,
    const float* __restrict__ kernA, const float* __restrict__ kernB,
    const float* __restrict__ hc_bias,
    float* __restrict__ out)
{
    const int tid = threadIdx.x;
    const int pix = blockIdx.x * 256 + tid;
    const int og = blockIdx.y * 32;
    const int b = blockIdx.z;

    __shared__ float kA[64][32], kB[64][32];
    for (int idx = tid; idx < 64 * 32; idx += 256) {
        int oc = idx & 31, c = idx >> 5;
        kA[c][oc] = kernA[((size_t)b * 64 + og + oc) * 64 + c];
        kB[c][oc] = kernB[((size_t)b * 64 + og + oc) * 64 + c];
    }
    __syncthreads();

    float accA[32], accB[32];
#pragma unroll
    for (int i = 0; i < 32; i++) { accA[i] = 0.f; accB[i] = 0.f; }

    const float* rb = r + (size_t)b * CC * PLANE + pix;
    for (int c = 0; c < CC; c++) {
        float rv = rb[(size_t)c * PLANE];
#pragma unroll
        for (int oc = 0; oc < 32; oc++) {
            accA[oc] += kA[c][oc] * rv;
            accB[oc] += kB[c][oc] * rv;
        }
    }

    float sv = smap[(size_t)b * PLANE + pix];
    float sig = 1.f / (1.f + expf(-sv));
    const float* xb = x + ((size_t)b * CC + og) * PLANE + pix;
    float* ob = out + ((size_t)b * CC + og) * PLANE + pix;
#pragma unroll
    for (int oc = 0; oc < 32; oc++) {
        ob[(size_t)oc * PLANE] = xb[(size_t)oc * PLANE] + hc_bias[og + oc]
                               + sig * accA[oc] + accB[oc];
    }
}

extern "C" void kernel_launch(void* const* d_in, const int* in_sizes, int n_in,
                              void* d_out, int out_size, void* d_ws, size_t ws_size,
                              hipStream_t stream) {
    const float* x   = (const float*)d_in[0];
    const float* h   = (const float*)d_in[1];
    const float* c1w = (const float*)d_in[2];
    const float* c1b = (const float*)d_in[3];
    const float* pa  = (const float*)d_in[4];
    const float* c2w = (const float*)d_in[5];
    const float* c2b = (const float*)d_in[6];
    const float* saw = (const float*)d_in[7];
    const float* sab = (const float*)d_in[8];
    const float* cw1 = (const float*)d_in[9];
    const float* cb1 = (const float*)d_in[10];
    const float* caa = (const float*)d_in[11];
    const float* cw2 = (const float*)d_in[12];
    const float* cb2 = (const float*)d_in[13];
    const float* fcw = (const float*)d_in[14];
    const float* fcb = (const float*)d_in[15];
    const float* k1w = (const float*)d_in[16];
    const float* k1b = (const float*)d_in[17];
    const float* k2w = (const float*)d_in[18];
    const float* k2b = (const float*)d_in[19];
    const float* k3w = (const float*)d_in[20];
    const float* k3b = (const float*)d_in[21];
    const float* hcb = (const float*)d_in[22];
    float* out = (float*)d_out;

    char* ws = (char*)d_ws;
    const size_t SZ_R = (size_t)8 * CC * PLANE * sizeof(float); // 134,217,728
    uint*  r1p = (uint*)ws;                    // conv1 out, bf16 ic-pair packed (67MB)
    float* r   = (float*)(ws + SZ_R);          // conv2 out, fp32
    // small buffers reuse the r1p region AFTER convs complete
    float* amx   = (float*)ws;
    float* smap  = (float*)(ws + (size_t)8 * 2 * PLANE * 4);
    float* g     = (float*)(ws + (size_t)8 * 3 * PLANE * 4);
    float* kernA = (float*)(ws + (size_t)8 * 3 * PLANE * 4 + 4096);
    float* kernB = kernA + (size_t)8 * 64 * 64;

    // weight packs live in d_out (dead until final_kernel overwrites it)
    uint* wsp = (uint*)d_out;
    uint* wh1 = wsp;          uint* wl1 = wsp + 18432;
    uint* wh2 = wsp + 36864;  uint* wl2 = wsp + 55296;

    wprep_kernel<<<dim3(72, 2), 256, 0, stream>>>(c1w, c2w, wh1, wl1, wh2, wl2);

    dim3 cgrid(WW / 32, HH / 8, 8);  // (8, 32, 8)
    conv_mfma<1><<<cgrid, 256, 0, stream>>>(x, nullptr, wh1, wl1, c1b, pa, r1p, nullptr);
    conv_mfma<2><<<cgrid, 256, 0, stream>>>(nullptr, r1p, wh2, wl2, c2b, nullptr, nullptr, r);

    hipMemsetAsync(g, 0, 512 * sizeof(float), stream);
    stats_kernel<<<dim3(PLANE / 256, 8), 256, 0, stream>>>(r, amx, g);
    saconv_kernel<<<dim3(PLANE / 256, 8), 256, 0, stream>>>(amx, saw, sab, smap);
    mlp_kernel<<<8, 256, 0, stream>>>(h, g, cw1, cb1, caa, cw2, cb2,
                                      fcw, fcb, k1w, k1b, k2w, k2b, k3w, k3b,
                                      kernA, kernB);
    final_kernel<<<dim3(PLANE / 256, 2, 8), 256, 0, stream>>>(
        x, r, smap, kernA, kernB, hcb, out);
}